// Round 5
// baseline (4271.026 us; speedup 1.0000x reference)
//
#include <hip/hip_runtime.h>

typedef unsigned short u16;
typedef unsigned int   u32;
typedef unsigned long long u64;
typedef __attribute__((ext_vector_type(8))) short short8;   // 8 x bf16 (4 VGPR)
typedef __attribute__((ext_vector_type(4))) float f32x4;

#define NB   64      // batch
#define TS   512     // timesteps
#define HD   512     // hidden
#define RG   4       // row-groups / chains (16 batch rows each)
#define CG   16      // col-groups per chain (32 h-cols each)
#define NBLK (RG*CG) // 64 blocks, 512 threads
#define HROW 256     // tagged u64 per h row (2 bf16 + tag per u64)
#define SLOT (NB*HROW)

__device__ __forceinline__ u16 f2bf(float x) {
    union { float f; u32 i; } v; v.f = x;
    u32 r = (v.i + 0x7fffu + ((v.i >> 16) & 1u)) >> 16;
    return (u16)r;
}
__device__ __forceinline__ u32 pack2bf(float a, float b) {
    return (u32)f2bf(a) | ((u32)f2bf(b) << 16);
}
__device__ __forceinline__ float sigmf(float x) { return 1.0f / (1.0f + __expf(-x)); }
__device__ __forceinline__ float tanhf_fast(float x) { return 1.0f - 2.0f / (__expf(2.0f * x) + 1.0f); }

// ---- x: f32 -> bf16, elementwise (one-time) -------------------------------
__global__ void cvt_x_k(const float* __restrict__ in, u16* __restrict__ out, int n) {
    int i = (blockIdx.x * blockDim.x + threadIdx.x) * 8;
    const int stride = gridDim.x * blockDim.x * 8;
    for (; i < n; i += stride) {
        const f32x4 a = *(const f32x4*)(in + i);
        const f32x4 b = *(const f32x4*)(in + i + 4);
        u32 q[4];
        q[0] = pack2bf(a[0], a[1]);
        q[1] = pack2bf(a[2], a[3]);
        q[2] = pack2bf(b[0], b[1]);
        q[3] = pack2bf(b[2], b[3]);
        *(f32x4*)(out + i) = *(f32x4*)q;
    }
}

// ---- transpose + f32->bf16 convert ---------------------------------------
__global__ void transpose_cvt_k(const float* __restrict__ in, u16* __restrict__ out,
                                int R, int C) {
    __shared__ float tile[32][33];
    const int c0 = blockIdx.x * 32;
    const int r0 = blockIdx.y * 32;
    const int tx = threadIdx.x & 31;
    const int ty = threadIdx.x >> 5;
#pragma unroll
    for (int i = 0; i < 32; i += 8)
        tile[ty + i][tx] = in[(size_t)(r0 + ty + i) * C + c0 + tx];
    __syncthreads();
#pragma unroll
    for (int i = 0; i < 32; i += 8)
        out[(size_t)(c0 + ty + i) * R + r0 + tx] = f2bf(tile[tx][ty + i]);
}

// ---- epoch bump (1 thread): makes tags unique per launch/replay -----------
__global__ void epoch_k(u32* e) {
    __hip_atomic_fetch_add(e, 1u, __ATOMIC_RELAXED, __HIP_MEMORY_SCOPE_AGENT);
}

__device__ __forceinline__ void load16_agent(u64* hq, const u64* p) {
#pragma unroll
    for (int i = 0; i < 16; ++i)
        hq[i] = __hip_atomic_load(p + i * 16, __ATOMIC_RELAXED,
                                  __HIP_MEMORY_SCOPE_AGENT);
}
__device__ __forceinline__ u32 tagmiss16(const u64* hq, u32 tagv) {
    u32 stale = 0;
#pragma unroll
    for (int i = 0; i < 16; ++i) stale |= ((u32)hq[i]) ^ tagv;
    return stale;
}

// ---- persistent fused LSTM ------------------------------------------------
// 64 blocks (r=bid&3 chain of 16 batch rows, cg=bid>>2 col-group of 32 h-cols).
// MFMA with A=W (operand swap): C/D col = batch (lane&15), row = kq*4+j with
// W rows permuted so reg j = gate j of hcol (8p + 4*tile + kq) -> one lane's
// f32x4 holds all 4 gates of ONE output element; elementwise is lane-local.
// 8 waves = 4 pairs x {finisher (K 0..255), poller (K 256..511)}.
// Pollers: poll h (tagged agent-atomic u64s), share via swizzled dbuf LDS,
// hand partial gates to partner via LDS pair-flag (release/acquire).
// Finishers: merge, elementwise, publish IMMEDIATELY. One barrier per step.
__global__ __launch_bounds__(512, 2) void lstm_fused(
    const u16*   __restrict__ xbg,  // (64,512,512) bf16
    const u16*   __restrict__ WtX,  // (2048,512) bf16 = W_xh^T
    const u16*   __restrict__ WtH,  // (2048,512) bf16 = W_hh^T
    const float* __restrict__ bxh,  // (2048) f32
    const float* __restrict__ bhh,  // (2048) f32
    u64*   __restrict__ hbuf,       // ring: (4 slots, 64 rows, 256 tagged u64)
    float* __restrict__ y,          // (64,512,512) f32
    u32*   __restrict__ epoch)      // [0] persistent epoch
{
    const int bid  = blockIdx.x;
    const int r    = bid & 3;
    const int cg   = bid >> 2;          // 0..15
    const int tid  = threadIdx.x;
    const int lane = tid & 63;
    const int wv   = tid >> 6;          // 0..7
    const int p    = wv & 3;            // pair id
    const int kh   = wv >> 2;           // 0 = finisher, 1 = poller
    const int m15  = lane & 15;
    const int kq   = lane >> 4;         // 0..3
    const int n0   = r * 16;
    const int kbase = kh * 256;

    __shared__ __align__(16) u32 ldsH[2][16 * 256];    // dbuf, XOR-swizzled
    __shared__ f32x4 pbufA[4][64];
    __shared__ f32x4 pbufB[4][64];
    __shared__ u32 pflag[4];
    __shared__ u32 sEpoch;

    if (tid == 0)
        sEpoch = __hip_atomic_load(epoch, __ATOMIC_RELAXED, __HIP_MEMORY_SCOPE_AGENT);
    if (tid < 4) pflag[tid] = 0;
    __syncthreads();
    const u32 tagbase = sEpoch << 10;   // t+1 <= 512 fits in 10 bits

    // --- preload W fragments as A-operand: row m = gate-col within 2 tiles.
    // m -> (gate = m&3, hcol = 8p + 4*tile + (m>>2))
    short8 wx[2][8], wh[2][8];
#pragma unroll
    for (int tt = 0; tt < 2; ++tt) {
        const int gcolA = (m15 & 3) * 512 + cg * 32 + 8 * p + 4 * tt + (m15 >> 2);
        const u16* px = WtX + (size_t)gcolA * 512 + kbase + kq * 8;
        const u16* ph = WtH + (size_t)gcolA * 512 + kbase + kq * 8;
#pragma unroll
        for (int kc = 0; kc < 8; ++kc) {
            wx[tt][kc] = *(const short8*)(px + kc * 32);
            wh[tt][kc] = *(const short8*)(ph + kc * 32);
        }
    }

    // finisher element params: lane -> (batch=m15, hcol hc0 and hc0+4)
    const int hc0 = cg * 32 + 8 * p + kq;
    const float bI0 = bxh[hc0]        + bhh[hc0];
    const float bF0 = bxh[512 + hc0]  + bhh[512 + hc0];
    const float bG0 = bxh[1024 + hc0] + bhh[1024 + hc0];
    const float bO0 = bxh[1536 + hc0] + bhh[1536 + hc0];
    const float bI1 = bxh[hc0 + 4]        + bhh[hc0 + 4];
    const float bF1 = bxh[512 + hc0 + 4]  + bhh[512 + hc0 + 4];
    const float bG1 = bxh[1024 + hc0 + 4] + bhh[1024 + hc0 + 4];
    const float bO1 = bxh[1536 + hc0 + 4] + bhh[1536 + hc0 + 4];
    float c0st = 0.0f, c1st = 0.0f;

    // poller params: rows 4p + (lane>>4); u64 col lq + 16*i
    const int lrow4 = 4 * p + (lane >> 4);
    const int lq    = lane & 15;
    const int swzP  = (lrow4 & 7) << 2;

    // ---- seed x fragments for t=0 (B-operand: n=batch m15, k=kbase+kq*8+kc*32+j)
    short8 xb[8];
    {
        const u16* xg = xbg + (size_t)(n0 + m15) * TS * HD + kbase + kq * 8;
#pragma unroll
        for (int kc = 0; kc < 8; ++kc) xb[kc] = *(const short8*)(xg + kc * 32);
    }

    u64 hq[16];

    for (int t = 0; t < TS; ++t) {
        // ---- 1. x-part MFMA (A=W, B=x)
        f32x4 A00 = {0.f,0.f,0.f,0.f}, A01 = {0.f,0.f,0.f,0.f};
        f32x4 A10 = {0.f,0.f,0.f,0.f}, A11 = {0.f,0.f,0.f,0.f};
#pragma unroll
        for (int kc = 0; kc < 8; kc += 2) {
            A00 = __builtin_amdgcn_mfma_f32_16x16x32_bf16(wx[0][kc],   xb[kc],   A00, 0, 0, 0);
            A10 = __builtin_amdgcn_mfma_f32_16x16x32_bf16(wx[1][kc],   xb[kc],   A10, 0, 0, 0);
            A01 = __builtin_amdgcn_mfma_f32_16x16x32_bf16(wx[0][kc+1], xb[kc+1], A01, 0, 0, 0);
            A11 = __builtin_amdgcn_mfma_f32_16x16x32_bf16(wx[1][kc+1], xb[kc+1], A11, 0, 0, 0);
        }

        // ---- 2. xb(t+1) issue: a full iteration of slack before its use
        if (t + 1 < TS) {
            const u16* xg = xbg + ((size_t)(n0 + m15) * TS + (t + 1)) * HD + kbase + kq * 8;
#pragma unroll
            for (int kc = 0; kc < 8; ++kc) xb[kc] = *(const short8*)(xg + kc * 32);
        }

        // ---- 3. poller: poll-check (loads issued last iter), share via LDS dbuf
        if (kh == 1 && t > 0) {
            const u64* gsrc = hbuf + (size_t)((t - 1) & 3) * SLOT
                            + (size_t)(n0 + lrow4) * HROW + lq;
            const u32 tagv = tagbase | (u32)t;
            int spins = 0;
            while (!__all(tagmiss16(hq, tagv) == 0u)) {
                if (++spins > 6) __builtin_amdgcn_s_sleep(1);
                load16_agent(hq, gsrc);
            }
            u32* lw = &ldsH[t & 1][lrow4 * 256];
#pragma unroll
            for (int i = 0; i < 16; ++i)
                lw[(lq + 16 * i) ^ swzP] = (u32)(hq[i] >> 32);
        }

        // ---- 4. the step's only barrier
        __syncthreads();

        // ---- 5. h-part MFMA from swizzled LDS (B-operand = h)
        if (t > 0) {
            const u32* lb = &ldsH[t & 1][m15 * 256];
            const int swzr = (m15 & 7) << 2;
            const int b32 = kh * 128;
#pragma unroll
            for (int kc = 0; kc < 8; kc += 2) {
                short8 h0 = *(const short8*)(lb + ((b32 + kc * 16 + kq * 4) ^ swzr));
                short8 h1 = *(const short8*)(lb + ((b32 + (kc + 1) * 16 + kq * 4) ^ swzr));
                A00 = __builtin_amdgcn_mfma_f32_16x16x32_bf16(wh[0][kc],   h0, A00, 0, 0, 0);
                A10 = __builtin_amdgcn_mfma_f32_16x16x32_bf16(wh[1][kc],   h0, A10, 0, 0, 0);
                A01 = __builtin_amdgcn_mfma_f32_16x16x32_bf16(wh[0][kc+1], h1, A01, 0, 0, 0);
                A11 = __builtin_amdgcn_mfma_f32_16x16x32_bf16(wh[1][kc+1], h1, A11, 0, 0, 0);
            }
        }

        if (kh == 1) {
            // ---- 6. issue next-step polls (in flight through the step tail)
            if (t + 1 < TS) {
                const u64* gsrc = hbuf + (size_t)(t & 3) * SLOT
                                + (size_t)(n0 + lrow4) * HROW + lq;
                load16_agent(hq, gsrc);
            }
            // ---- 7. hand partial gates to partner (pair-local sync, no barrier)
            pbufA[p][lane] = A00 + A01;
            pbufB[p][lane] = A10 + A11;
            __hip_atomic_store(&pflag[p], (u32)(t + 1), __ATOMIC_RELEASE,
                               __HIP_MEMORY_SCOPE_WORKGROUP);
        } else {
            // ---- finisher: merge partner partials
            int fs = 0;
            while (__hip_atomic_load(&pflag[p], __ATOMIC_ACQUIRE,
                                     __HIP_MEMORY_SCOPE_WORKGROUP) < (u32)(t + 1)) {
                if (++fs > 16) __builtin_amdgcn_s_sleep(1);
            }
            const f32x4 g0 = A00 + A01 + pbufA[p][lane];
            const f32x4 g1 = A10 + A11 + pbufB[p][lane];

            // ---- elementwise: lane-local, all 4 gates in g0/g1
            const float i0 = sigmf(g0[0] + bI0);
            const float f0 = sigmf(g0[1] + bF0);
            const float gg0 = tanhf_fast(g0[2] + bG0);
            const float o0 = sigmf(g0[3] + bO0);
            c0st = f0 * c0st + i0 * gg0;
            const float h0v = o0 * tanhf_fast(c0st);

            const float i1 = sigmf(g1[0] + bI1);
            const float f1 = sigmf(g1[1] + bF1);
            const float gg1 = tanhf_fast(g1[2] + bG1);
            const float o1 = sigmf(g1[3] + bO1);
            c1st = f1 * c1st + i1 * gg1;
            const float h1v = o1 * tanhf_fast(c1st);

            // ---- publish FIRST (critical path), then y
            const u32 me0 = (u32)f2bf(h0v);
            const u32 me1 = (u32)f2bf(h1v);
            const u32 nb0 = (u32)__shfl_xor((int)me0, 16);   // partner kq^1
            const u32 nb1 = (u32)__shfl_xor((int)me1, 16);
            if ((kq & 1) == 0) {
                const u32 tg = tagbase | (u32)(t + 1);
                const u64 v0 = ((u64)(me0 | (nb0 << 16)) << 32) | (u64)tg;
                const u64 v1 = ((u64)(me1 | (nb1 << 16)) << 32) | (u64)tg;
                // u64 col = hcol/2 = cg*16 + 4p + kq/2   (cg*16 was the r4 bug)
                u64* d0 = hbuf + (size_t)(t & 3) * SLOT
                        + (size_t)(n0 + m15) * HROW + cg * 16 + 4 * p + (kq >> 1);
                __hip_atomic_store(d0,     v0, __ATOMIC_RELAXED, __HIP_MEMORY_SCOPE_AGENT);
                __hip_atomic_store(d0 + 2, v1, __ATOMIC_RELAXED, __HIP_MEMORY_SCOPE_AGENT);
            }
            float* yp = y + ((size_t)(n0 + m15) * TS + t) * HD + hc0;
            yp[0] = h0v;
            yp[4] = h1v;
        }
    }
}

extern "C" void kernel_launch(void* const* d_in, const int* in_sizes, int n_in,
                              void* d_out, int out_size, void* d_ws, size_t ws_size,
                              hipStream_t stream) {
    const float* x   = (const float*)d_in[0];
    const float* wxh = (const float*)d_in[1];
    const float* whh = (const float*)d_in[2];
    const float* bxh = (const float*)d_in[3];
    const float* bhh = (const float*)d_in[4];
    float* y = (float*)d_out;

    char* ws = (char*)d_ws;
    u32* epoch = (u32*)ws;                                    // persistent, never cleared
    u64* hbuf  = (u64*)(ws + 4096);                           // 512 KB ring (4 slots)
    u16* WtX   = (u16*)(ws + 4096 + (size_t)4 * SLOT * 8);
    u16* WtH   = (u16*)((char*)WtX + (size_t)2048 * 512 * 2);
    u16* xbg   = (u16*)((char*)WtH + (size_t)2048 * 512 * 2); // 32 MB

    epoch_k<<<1, 1, 0, stream>>>(epoch);                      // unique tags per replay
    (void)hipMemsetAsync(hbuf, 0, (size_t)4 * SLOT * 8, stream);

    cvt_x_k<<<2048, 256, 0, stream>>>(x, xbg, NB * TS * HD);

    dim3 tgrid(2048 / 32, 512 / 32);
    transpose_cvt_k<<<tgrid, 256, 0, stream>>>(wxh, WtX, 512, 2048);
    transpose_cvt_k<<<tgrid, 256, 0, stream>>>(whh, WtH, 512, 2048);

    lstm_fused<<<dim3(NBLK), dim3(512), 0, stream>>>(xbg, WtX, WtH, bxh, bhh,
                                                     hbuf, y, epoch);
}